// Round 1
// baseline (440.042 us; speedup 1.0000x reference)
//
#include <hip/hip_runtime.h>

#define LRELU_ALPHA 0.2f

constexpr int NN    = 4096;
constexpr int FIN   = 512;
constexpr int NH    = 8;
constexpr int FOUT  = 64;
constexpr int NFLAT = NH * FOUT; // 512

// ---------------- Kernel A: Wh = x @ W (fp32, 64x64 tile, 4x4/thread) ----------------
__global__ __launch_bounds__(256) void k_gemm_xw(const float* __restrict__ x,
                                                 const float* __restrict__ W,
                                                 float* __restrict__ Wh) {
    __shared__ alignas(16) float As[16][68]; // As[k][m], padded
    __shared__ alignas(16) float Bs[16][68]; // Bs[k][n], padded
    const int t  = threadIdx.x;
    const int bm = blockIdx.x * 64;
    const int bn = blockIdx.y * 64;
    const int ti = t >> 4, tf = t & 15;
    const int i0 = ti * 4, f0 = tf * 4;
    const int mA = t >> 2, kqA = t & 3;   // A-load mapping
    const int kB = t >> 4, fqB = t & 15;  // B-load mapping
    float acc[4][4] = {};
    for (int k0 = 0; k0 < FIN; k0 += 16) {
        float4 a4 = *(const float4*)&x[(size_t)(bm + mA) * FIN + k0 + kqA * 4];
        float4 b4 = *(const float4*)&W[(size_t)(k0 + kB) * NFLAT + bn + fqB * 4];
        __syncthreads();
        As[kqA * 4 + 0][mA] = a4.x;
        As[kqA * 4 + 1][mA] = a4.y;
        As[kqA * 4 + 2][mA] = a4.z;
        As[kqA * 4 + 3][mA] = a4.w;
        *(float4*)&Bs[kB][fqB * 4] = b4;
        __syncthreads();
        #pragma unroll
        for (int k = 0; k < 16; ++k) {
            float4 av = *(const float4*)&As[k][i0];
            float4 bv = *(const float4*)&Bs[k][f0];
            float aa[4] = {av.x, av.y, av.z, av.w};
            #pragma unroll
            for (int ii = 0; ii < 4; ++ii) {
                acc[ii][0] += aa[ii] * bv.x;
                acc[ii][1] += aa[ii] * bv.y;
                acc[ii][2] += aa[ii] * bv.z;
                acc[ii][3] += aa[ii] * bv.w;
            }
        }
    }
    #pragma unroll
    for (int ii = 0; ii < 4; ++ii) {
        float4 o = make_float4(acc[ii][0], acc[ii][1], acc[ii][2], acc[ii][3]);
        *(float4*)&Wh[(size_t)(bm + i0 + ii) * NFLAT + bn + f0] = o;
    }
}

// ---------------- Kernel B: f1[n,h] = Wh[n,h,:]·a1, f2 = Wh·a2 (stored transposed [h][n]) ----
__global__ __launch_bounds__(256) void k_f12(const float* __restrict__ Wh,
                                             const float* __restrict__ a,
                                             float* __restrict__ f1T,
                                             float* __restrict__ f2T) {
    const int gw   = blockIdx.x * 4 + (threadIdx.x >> 6); // one wave per (n,h)
    const int lane = threadIdx.x & 63;
    const int n = gw >> 3, h = gw & 7;
    float v  = Wh[(size_t)n * NFLAT + h * FOUT + lane];
    float s1 = v * a[lane];
    float s2 = v * a[64 + lane];
    #pragma unroll
    for (int off = 32; off > 0; off >>= 1) {
        s1 += __shfl_xor(s1, off);
        s2 += __shfl_xor(s2, off);
    }
    if (lane == 0) {
        f1T[h * NN + n] = s1;
        f2T[h * NN + n] = s2;
    }
}

// ---------------- Kernel C: fused masked softmax + PV ----------------
// One block = 64 rows x 1 head. No max-subtraction needed (|e| <= ~10, exp safe in fp32).
__global__ __launch_bounds__(256) void k_attn(const int* __restrict__ adj,
                                              const float* __restrict__ Wh,
                                              const float* __restrict__ f1T,
                                              const float* __restrict__ f2T,
                                              float* __restrict__ out) {
    __shared__ alignas(16) float Ps[64][68];   // P[i][jj], padded (row stride 68 -> 2-way max)
    __shared__ alignas(16) float Whs[64][68];  // Wh[jj][f], padded
    __shared__ float f1s[64];
    __shared__ float f2s[64];
    __shared__ float lsum[64];
    const int t   = threadIdx.x;
    const int gi0 = blockIdx.x * 64;
    const int h   = blockIdx.y;
    if (t < 64) { f1s[t] = f1T[h * NN + gi0 + t]; lsum[t] = 0.f; }
    const int ti = t >> 4, tf = t & 15;
    const int i0 = ti * 4, f0 = tf * 4;
    const int iP = t >> 2, jq = t & 3;
    float acc[4][4] = {};
    for (int jt = 0; jt < 64; ++jt) {
        const int gj0 = jt * 64;
        __syncthreads(); // previous tile's GEMM reads complete
        if (t < 64) f2s[t] = f2T[h * NN + gj0 + t];
        #pragma unroll
        for (int qq = 0; qq < 4; ++qq) { // stage Wh slice: row iP, 4 quads per thread
            int c = (jq + qq * 4) * 4;
            float4 wv = *(const float4*)&Wh[(size_t)(gj0 + iP) * NFLAT + h * FOUT + c];
            *(float4*)&Whs[iP][c] = wv;
        }
        __syncthreads(); // f2s/Whs visible
        // ---- P tile: p = adj ? exp(lrelu(f1+f2)) : 0 ----
        const float f1v = f1s[iP];
        float lpart = 0.f;
        const int* adjrow = &adj[(size_t)(gi0 + iP) * NN + gj0 + jq * 16];
        #pragma unroll
        for (int q = 0; q < 4; ++q) {
            int4 av = *(const int4*)&adjrow[q * 4];
            int jj = jq * 16 + q * 4;
            float4 p;
            float e0 = f1v + f2s[jj + 0]; e0 = e0 >= 0.f ? e0 : LRELU_ALPHA * e0; p.x = av.x > 0 ? __expf(e0) : 0.f;
            float e1 = f1v + f2s[jj + 1]; e1 = e1 >= 0.f ? e1 : LRELU_ALPHA * e1; p.y = av.y > 0 ? __expf(e1) : 0.f;
            float e2 = f1v + f2s[jj + 2]; e2 = e2 >= 0.f ? e2 : LRELU_ALPHA * e2; p.z = av.z > 0 ? __expf(e2) : 0.f;
            float e3 = f1v + f2s[jj + 3]; e3 = e3 >= 0.f ? e3 : LRELU_ALPHA * e3; p.w = av.w > 0 ? __expf(e3) : 0.f;
            *(float4*)&Ps[iP][jj] = p;
            lpart += p.x + p.y + p.z + p.w;
        }
        atomicAdd(&lsum[iP], lpart);
        __syncthreads(); // Ps visible
        // ---- PV GEMM: acc[i][f] += sum_jj P[i][jj] * Wh[jj][f] ----
        #pragma unroll
        for (int jjq = 0; jjq < 16; ++jjq) {
            float4 wv[4], pv[4];
            #pragma unroll
            for (int q = 0; q < 4; ++q) wv[q] = *(const float4*)&Whs[jjq * 4 + q][f0];
            #pragma unroll
            for (int ii = 0; ii < 4; ++ii) pv[ii] = *(const float4*)&Ps[i0 + ii][jjq * 4];
            #pragma unroll
            for (int ii = 0; ii < 4; ++ii) {
                float pp[4] = {pv[ii].x, pv[ii].y, pv[ii].z, pv[ii].w};
                #pragma unroll
                for (int q = 0; q < 4; ++q) {
                    acc[ii][0] += pp[q] * wv[q].x;
                    acc[ii][1] += pp[q] * wv[q].y;
                    acc[ii][2] += pp[q] * wv[q].z;
                    acc[ii][3] += pp[q] * wv[q].w;
                }
            }
        }
    }
    __syncthreads(); // lsum complete
    #pragma unroll
    for (int ii = 0; ii < 4; ++ii) {
        float inv = 1.0f / (lsum[i0 + ii] * (float)NH);
        #pragma unroll
        for (int ff = 0; ff < 4; ++ff)
            atomicAdd(&out[(size_t)(gi0 + i0 + ii) * FOUT + f0 + ff], acc[ii][ff] * inv);
    }
}

extern "C" void kernel_launch(void* const* d_in, const int* in_sizes, int n_in,
                              void* d_out, int out_size, void* d_ws, size_t ws_size,
                              hipStream_t stream) {
    const float* x   = (const float*)d_in[0];
    const int*   adj = (const int*)d_in[1];
    const float* W   = (const float*)d_in[2];
    const float* a   = (const float*)d_in[3];
    float* out = (float*)d_out;
    // workspace: Wh (8 MiB) + f1T/f2T (128 KiB each)
    float* Wh  = (float*)d_ws;
    float* f1T = Wh + (size_t)NN * NFLAT;
    float* f2T = f1T + (size_t)NH * NN;

    hipMemsetAsync(d_out, 0, (size_t)out_size * sizeof(float), stream);
    k_gemm_xw<<<dim3(NN / 64, NFLAT / 64), 256, 0, stream>>>(x, W, Wh);
    k_f12<<<dim3(NN * NH / 4), 256, 0, stream>>>(Wh, a, f1T, f2T);
    k_attn<<<dim3(NN / 64, NH), 256, 0, stream>>>(adj, Wh, f1T, f2T, out);
}

// Round 2
// 167.102 us; speedup vs baseline: 2.6334x; 2.6334x over previous
//
#include <hip/hip_runtime.h>

#define LRELU_ALPHA 0.2f

constexpr int NN    = 4096;
constexpr int FIN   = 512;
constexpr int NH    = 8;
constexpr int FOUT  = 64;
constexpr int NFLAT = NH * FOUT; // 512

typedef __attribute__((ext_vector_type(8))) __bf16 bf16x8;
typedef __attribute__((ext_vector_type(4))) float f32x4;

// ---------------- Kernel A: Wh = x @ W (fp32, 64x64 tile, 4x4/thread) ----------------
__global__ __launch_bounds__(256) void k_gemm_xw(const float* __restrict__ x,
                                                 const float* __restrict__ W,
                                                 float* __restrict__ Wh) {
    __shared__ alignas(16) float As[16][68];
    __shared__ alignas(16) float Bs[16][68];
    const int t  = threadIdx.x;
    const int bm = blockIdx.x * 64;
    const int bn = blockIdx.y * 64;
    const int ti = t >> 4, tf = t & 15;
    const int i0 = ti * 4, f0 = tf * 4;
    const int mA = t >> 2, kqA = t & 3;
    const int kB = t >> 4, fqB = t & 15;
    float acc[4][4] = {};
    for (int k0 = 0; k0 < FIN; k0 += 16) {
        float4 a4 = *(const float4*)&x[(size_t)(bm + mA) * FIN + k0 + kqA * 4];
        float4 b4 = *(const float4*)&W[(size_t)(k0 + kB) * NFLAT + bn + fqB * 4];
        __syncthreads();
        As[kqA * 4 + 0][mA] = a4.x;
        As[kqA * 4 + 1][mA] = a4.y;
        As[kqA * 4 + 2][mA] = a4.z;
        As[kqA * 4 + 3][mA] = a4.w;
        *(float4*)&Bs[kB][fqB * 4] = b4;
        __syncthreads();
        #pragma unroll
        for (int k = 0; k < 16; ++k) {
            float4 av = *(const float4*)&As[k][i0];
            float4 bv = *(const float4*)&Bs[k][f0];
            float aa[4] = {av.x, av.y, av.z, av.w};
            #pragma unroll
            for (int ii = 0; ii < 4; ++ii) {
                acc[ii][0] += aa[ii] * bv.x;
                acc[ii][1] += aa[ii] * bv.y;
                acc[ii][2] += aa[ii] * bv.z;
                acc[ii][3] += aa[ii] * bv.w;
            }
        }
    }
    #pragma unroll
    for (int ii = 0; ii < 4; ++ii) {
        float4 o = make_float4(acc[ii][0], acc[ii][1], acc[ii][2], acc[ii][3]);
        *(float4*)&Wh[(size_t)(bm + i0 + ii) * NFLAT + bn + f0] = o;
    }
}

// ---------------- Kernel B: f1/f2 (stored transposed [h][n]) ----------------
__global__ __launch_bounds__(256) void k_f12(const float* __restrict__ Wh,
                                             const float* __restrict__ a,
                                             float* __restrict__ f1T,
                                             float* __restrict__ f2T) {
    const int gw   = blockIdx.x * 4 + (threadIdx.x >> 6);
    const int lane = threadIdx.x & 63;
    const int n = gw >> 3, h = gw & 7;
    float v  = Wh[(size_t)n * NFLAT + h * FOUT + lane];
    float s1 = v * a[lane];
    float s2 = v * a[64 + lane];
    #pragma unroll
    for (int off = 32; off > 0; off >>= 1) {
        s1 += __shfl_xor(s1, off);
        s2 += __shfl_xor(s2, off);
    }
    if (lane == 0) {
        f1T[h * NN + n] = s1;
        f2T[h * NN + n] = s2;
    }
}

// ---------------- Kernel: pack adj into bitmask ----------------
__global__ __launch_bounds__(256) void k_bitmask(const int* __restrict__ adj,
                                                 unsigned long long* __restrict__ bm) {
    size_t idx = (size_t)blockIdx.x * 256 + threadIdx.x;
    int v = adj[idx];
    unsigned long long b = __ballot(v > 0);
    if ((threadIdx.x & 63) == 0) bm[idx >> 6] = b;
}

// ---------------- Kernel: WhT[h][f][j] bf16, pre-swizzled per 64-j tile ----------------
// Within each 64-j tile, the 8-element j-group is stored at position (jg ^ (f&7)).
// Then a LINEAR global_load_lds into LDS yields content such that
// LDS[(f*128 + j*2) ^ ((f&7)<<4)] == Wh[j][h*64+f]  (T2 swizzle, conflict-free b128 reads).
__global__ __launch_bounds__(256) void k_prep_wht(const float* __restrict__ Wh,
                                                  __bf16* __restrict__ whtsw) {
    __shared__ alignas(16) float tile[64][68];
    const int t = threadIdx.x;
    const int T = blockIdx.x;   // j-tile
    const int h = blockIdx.y;
    {
        const int r = t >> 2, q = t & 3;
        const float4* src = (const float4*)&Wh[(size_t)(T * 64 + r) * NFLAT + h * 64 + q * 16];
        #pragma unroll
        for (int i = 0; i < 4; ++i)
            *(float4*)&tile[r][q * 16 + i * 4] = src[i];
    }
    __syncthreads();
    const int f = t >> 2;
    #pragma unroll
    for (int c = 0; c < 2; ++c) {
        int pg = (t & 3) * 2 + c;          // stored position
        int jg = pg ^ (f & 7);             // source j-group
        bf16x8 o;
        #pragma unroll
        for (int jo = 0; jo < 8; ++jo)
            o[jo] = (__bf16)tile[jg * 8 + jo][f];
        *(bf16x8*)&whtsw[((size_t)(h * 64 + f)) * NN + T * 64 + pg * 8] = o;
    }
}

// ---------------- Kernel C: fused masked softmax + PV via MFMA ----------------
__global__ __launch_bounds__(256) void k_attn(const unsigned long long* __restrict__ bm,
                                              const __bf16* __restrict__ whtsw,
                                              const float* __restrict__ f1T,
                                              const float* __restrict__ f2T,
                                              float* __restrict__ out) {
    __shared__ alignas(16) __bf16 Ps[2][64 * 64];
    __shared__ alignas(16) __bf16 Ws[2][64 * 64];
    __shared__ float f1s[64];
    __shared__ float lsum[64];

    const int t   = threadIdx.x;
    const int wv  = t >> 6, l = t & 63;
    const int gi0 = blockIdx.x * 64;
    const int h   = blockIdx.y;

    if (t < 64) f1s[t] = f1T[h * NN + gi0 + t];
    __syncthreads();

    // ---- P-compute ids: thread owns row ip, j-range [jq*16, jq*16+16) per tile ----
    const int ip = t >> 2;
    const int jq = t & 3;
    const float f1v = f1s[ip];
    const unsigned long long* bmrow = &bm[(size_t)(gi0 + ip) * 64];
    const int swP = (ip & 7) << 4;
    float lpart = 0.f;

    // ---- MFMA ids ----
    const int lm = l & 15, lk = l >> 4;
    const int iA    = wv * 16 + lm;
    const int baseA = iA * 128 + lk * 16;
    const int swA   = (iA & 7) << 4;
    const int swB   = (lm & 7) << 4;
    f32x4 acc[4] = {};

    const __bf16* wbase = &whtsw[(size_t)(h * 64) * NN];

    auto stage_W = [&](int jt, int bb) {
        #pragma unroll
        for (int k = 0; k < 2; ++k) {
            int n16 = wv * 64 + l + k * 256;
            int f = n16 >> 3, jg = n16 & 7;
            const __bf16* src = wbase + (size_t)f * NN + jt * 64 + jg * 8;
            __builtin_amdgcn_global_load_lds(
                (const __attribute__((address_space(1))) void*)src,
                (__attribute__((address_space(3))) void*)((char*)&Ws[bb][0] + (wv * 64 + k * 256) * 16),
                16, 0, 0);
        }
    };

    auto compute_P = [&](int jt, int bb) {
        unsigned long long w = bmrow[jt];
        unsigned m16 = (unsigned)((w >> (jq * 16)) & 0xFFFFULL);
        const float4* f2p = (const float4*)&f2T[h * NN + jt * 64 + jq * 16];
        #pragma unroll
        for (int c = 0; c < 2; ++c) {
            bf16x8 pk;
            #pragma unroll
            for (int qq = 0; qq < 2; ++qq) {
                float4 f2v = f2p[c * 2 + qq];
                float ee[4] = {f2v.x, f2v.y, f2v.z, f2v.w};
                #pragma unroll
                for (int e = 0; e < 4; ++e) {
                    float s = f1v + ee[e];
                    float lr = fmaxf(s, LRELU_ALPHA * s);
                    float p = __expf(lr);
                    p = (m16 & (1u << (c * 8 + qq * 4 + e))) ? p : 0.0f;
                    lpart += p;
                    pk[qq * 4 + e] = (__bf16)p;
                }
            }
            *(bf16x8*)((char*)&Ps[bb][0] + ((ip * 128 + (jq * 2 + c) * 16) ^ swP)) = pk;
        }
    };

    auto do_mfma = [&](int bb) {
        const char* pb = (const char*)&Ps[bb][0];
        const char* wb = (const char*)&Ws[bb][0];
        bf16x8 aF[2];
        #pragma unroll
        for (int ks = 0; ks < 2; ++ks)
            aF[ks] = *(const bf16x8*)(pb + ((baseA | (ks << 6)) ^ swA));
        #pragma unroll
        for (int q = 0; q < 4; ++q) {
            const int baseB = (q * 16 + lm) * 128 + lk * 16;
            #pragma unroll
            for (int ks = 0; ks < 2; ++ks) {
                bf16x8 bF = *(const bf16x8*)(wb + ((baseB | (ks << 6)) ^ swB));
                acc[q] = __builtin_amdgcn_mfma_f32_16x16x32_bf16(aF[ks], bF, acc[q], 0, 0, 0);
            }
        }
    };

    // prologue
    stage_W(0, 0);
    compute_P(0, 0);
    for (int jt = 0; jt < 64; ++jt) {
        const int cur = jt & 1, nxt = cur ^ 1;
        __syncthreads();
        if (jt < 63) {
            stage_W(jt + 1, nxt);
            compute_P(jt + 1, nxt);
        }
        do_mfma(cur);
    }

    // ---- row-sum reduce (4 threads per row are lanes l, l^1, l^2 of one wave) ----
    lpart += __shfl_xor(lpart, 1);
    lpart += __shfl_xor(lpart, 2);
    if (jq == 0) lsum[ip] = lpart;
    __syncthreads();

    // ---- epilogue: normalize + accumulate across heads ----
    float inv[4];
    #pragma unroll
    for (int r = 0; r < 4; ++r)
        inv[r] = 1.0f / (lsum[wv * 16 + lk * 4 + r] * (float)NH);
    #pragma unroll
    for (int q = 0; q < 4; ++q) {
        #pragma unroll
        for (int r = 0; r < 4; ++r) {
            int io = wv * 16 + lk * 4 + r;
            int fo = q * 16 + lm;
            atomicAdd(&out[(size_t)(gi0 + io) * FOUT + fo], acc[q][r] * inv[r]);
        }
    }
}

extern "C" void kernel_launch(void* const* d_in, const int* in_sizes, int n_in,
                              void* d_out, int out_size, void* d_ws, size_t ws_size,
                              hipStream_t stream) {
    const float* x   = (const float*)d_in[0];
    const int*   adj = (const int*)d_in[1];
    const float* W   = (const float*)d_in[2];
    const float* a   = (const float*)d_in[3];
    float* out = (float*)d_out;

    char* ws = (char*)d_ws;
    float* Wh   = (float*)ws;                        ws += (size_t)NN * NFLAT * 4;   // 8 MiB
    float* f1T  = (float*)ws;                        ws += (size_t)NH * NN * 4;      // 128 KiB
    float* f2T  = (float*)ws;                        ws += (size_t)NH * NN * 4;      // 128 KiB
    __bf16* whtsw = (__bf16*)ws;                     ws += (size_t)NFLAT * NN * 2;   // 4 MiB
    unsigned long long* bmask = (unsigned long long*)ws;                              // 2 MiB

    hipMemsetAsync(d_out, 0, (size_t)out_size * sizeof(float), stream);
    k_bitmask<<<dim3(NN * NN / 256), 256, 0, stream>>>(adj, bmask);
    k_gemm_xw<<<dim3(NN / 64, NFLAT / 64), 256, 0, stream>>>(x, W, Wh);
    k_f12<<<dim3(NN * NH / 4), 256, 0, stream>>>(Wh, a, f1T, f2T);
    k_prep_wht<<<dim3(64, NH), 256, 0, stream>>>(Wh, whtsw);
    k_attn<<<dim3(NN / 64, NH), 256, 0, stream>>>(bmask, whtsw, f1T, f2T, out);
}

// Round 3
// 136.671 us; speedup vs baseline: 3.2197x; 1.2227x over previous
//
#include <hip/hip_runtime.h>

#define LRELU_ALPHA 0.2f

constexpr int NN    = 4096;
constexpr int FIN   = 512;
constexpr int NH    = 8;
constexpr int FOUT  = 64;
constexpr int NFLAT = NH * FOUT; // 512
constexpr float LOG2E = 1.4426950408889634f;

typedef __attribute__((ext_vector_type(8))) __bf16 bf16x8;
typedef __attribute__((ext_vector_type(4))) float f32x4;

// ---------------- pack adj into bitmask ----------------
__global__ __launch_bounds__(256) void k_bitmask(const int* __restrict__ adj,
                                                 unsigned long long* __restrict__ bm) {
    size_t idx = (size_t)blockIdx.x * 256 + threadIdx.x;
    int v = adj[idx];
    unsigned long long b = __ballot(v > 0);
    if ((threadIdx.x & 63) == 0) bm[idx >> 6] = b;
}

// ---------------- Wa[k][o] = log2e * sum_f W[k][(o&7)*64+f] * a[(o>>3)*64+f] ----------------
__global__ __launch_bounds__(256) void k_wa(const float* __restrict__ W,
                                            const float* __restrict__ a,
                                            float* __restrict__ Wa) {
    const int t = threadIdx.x;
    const int k = blockIdx.x * 16 + (t >> 4);
    const int o = t & 15;
    const float* wrow = &W[(size_t)k * NFLAT + (o & 7) * 64];
    const float* av   = &a[(o >> 3) * 64];
    float acc = 0.f;
    #pragma unroll 8
    for (int f = 0; f < 64; ++f) acc = fmaf(wrow[f], av[f], acc);
    Wa[k * 16 + o] = acc * LOG2E;
}

// ---------------- f{1,2}T[h][n] = sum_k x[n][k] * Wa[k][o]  (log2e pre-scaled) ----------------
__global__ __launch_bounds__(256) void k_f12(const float* __restrict__ x,
                                             const float* __restrict__ Wa,
                                             float* __restrict__ f1T,
                                             float* __restrict__ f2T) {
    __shared__ float xs[16][512];     // quad-swizzled rows (conflict-free reads)
    __shared__ float was[512 * 16];
    const int t = threadIdx.x;
    const int n0 = blockIdx.x * 16;
    #pragma unroll
    for (int i = 0; i < 8; ++i) {
        int idx = t + i * 256;
        int r = idx >> 7, cq = idx & 127;
        *(float4*)&xs[r][(cq ^ (r & 3)) * 4] = *(const float4*)&x[(size_t)(n0 + r) * FIN + cq * 4];
        *(float4*)&was[idx * 4] = *(const float4*)&Wa[idx * 4];
    }
    __syncthreads();
    const int o = t & 15, nl = t >> 4;
    float acc = 0.f;
    #pragma unroll 4
    for (int kq = 0; kq < 128; ++kq) {
        float4 xv = *(const float4*)&xs[nl][(kq ^ (nl & 3)) * 4];
        int k0 = kq * 4;
        acc = fmaf(xv.x, was[(k0 + 0) * 16 + o], acc);
        acc = fmaf(xv.y, was[(k0 + 1) * 16 + o], acc);
        acc = fmaf(xv.z, was[(k0 + 2) * 16 + o], acc);
        acc = fmaf(xv.w, was[(k0 + 3) * 16 + o], acc);
    }
    float* dst = (o >> 3) ? f2T : f1T;
    dst[(o & 7) * NN + n0 + nl] = acc;
}

// ---------------- W -> wtsw[kt][f][64k] bf16, group g stored at g^(f&7) ----------------
__global__ __launch_bounds__(256) void k_prep_wt(const float* __restrict__ W,
                                                 __bf16* __restrict__ wtsw) {
    __shared__ float tile[64][68];
    const int t = threadIdx.x;
    const int kt = blockIdx.x;
    const int fb = blockIdx.y * 64;
    {
        const int kk = t >> 2, cq = (t & 3) * 16;
        #pragma unroll
        for (int i = 0; i < 4; ++i)
            *(float4*)&tile[kk][cq + i * 4] =
                *(const float4*)&W[(size_t)(kt * 64 + kk) * NFLAT + fb + cq + i * 4];
    }
    __syncthreads();
    const int fl = t >> 2;
    #pragma unroll
    for (int c = 0; c < 2; ++c) {
        int gs = (t & 3) * 2 + c;
        int g  = gs ^ (fl & 7);
        bf16x8 o;
        #pragma unroll
        for (int jo = 0; jo < 8; ++jo) o[jo] = (__bf16)tile[g * 8 + jo][fl];
        *(bf16x8*)&wtsw[((size_t)(kt * NFLAT + fb + fl)) * 64 + gs * 8] = o;
    }
}

// ---------------- Wh = bf16(x) @ bf16(W) via MFMA (fp32 out) ----------------
__global__ __launch_bounds__(256) void k_gemm(const float* __restrict__ x,
                                              const __bf16* __restrict__ wtsw,
                                              float* __restrict__ Wh) {
    __shared__ alignas(16) __bf16 Bs[2][64 * 64];
    const int t = threadIdx.x, wv = t >> 6, l = t & 63;
    const int bm = blockIdx.x * 64, bn = blockIdx.y * 64;
    const int lm = l & 15, lk = l >> 4;
    const int swB = (lm & 7) << 4;
    f32x4 acc[4] = {};

    auto stageB = [&](int kt, int bb) {
        #pragma unroll
        for (int kq = 0; kq < 2; ++kq) {
            int u = t + kq * 256;
            __builtin_amdgcn_global_load_lds(
                (const __attribute__((address_space(1))) void*)(wtsw + (size_t)(kt * NFLAT + bn) * 64 + u * 8),
                (__attribute__((address_space(3))) void*)((char*)&Bs[bb][0] + u * 16), 16, 0, 0);
        }
    };

    stageB(0, 0);
    const float* xrow = &x[(size_t)(bm + wv * 16 + lm) * FIN + lk * 8];
    for (int kt = 0; kt < 8; ++kt) {
        bf16x8 aF[2];
        #pragma unroll
        for (int ks = 0; ks < 2; ++ks) {
            float4 u0 = *(const float4*)&xrow[kt * 64 + ks * 32];
            float4 u1 = *(const float4*)&xrow[kt * 64 + ks * 32 + 4];
            bf16x8 af;
            af[0] = (__bf16)u0.x; af[1] = (__bf16)u0.y; af[2] = (__bf16)u0.z; af[3] = (__bf16)u0.w;
            af[4] = (__bf16)u1.x; af[5] = (__bf16)u1.y; af[6] = (__bf16)u1.z; af[7] = (__bf16)u1.w;
            aF[ks] = af;
        }
        __syncthreads();
        if (kt < 7) stageB(kt + 1, (kt + 1) & 1);
        const char* wb = (const char*)&Bs[kt & 1][0];
        #pragma unroll
        for (int q = 0; q < 4; ++q) {
            #pragma unroll
            for (int ks = 0; ks < 2; ++ks) {
                bf16x8 bF = *(const bf16x8*)(wb + (((q * 16 + lm) * 128 + lk * 16 + ks * 64) ^ swB));
                acc[q] = __builtin_amdgcn_mfma_f32_16x16x32_bf16(aF[ks], bF, acc[q], 0, 0, 0);
            }
        }
    }
    #pragma unroll
    for (int q = 0; q < 4; ++q)
        #pragma unroll
        for (int r = 0; r < 4; ++r)
            Wh[(size_t)(bm + wv * 16 + lk * 4 + r) * NFLAT + bn + q * 16 + lm] = acc[q][r];
}

// ---------------- Wh -> whtsw[h*64+f][j] bf16, pre-swizzled per 64-j tile ----------------
__global__ __launch_bounds__(256) void k_prep_wht(const float* __restrict__ Wh,
                                                  __bf16* __restrict__ whtsw) {
    __shared__ alignas(16) float tile[64][68];
    const int t = threadIdx.x;
    const int T = blockIdx.x;
    const int h = blockIdx.y;
    {
        const int r = t >> 2, q = t & 3;
        const float4* src = (const float4*)&Wh[(size_t)(T * 64 + r) * NFLAT + h * 64 + q * 16];
        #pragma unroll
        for (int i = 0; i < 4; ++i)
            *(float4*)&tile[r][q * 16 + i * 4] = src[i];
    }
    __syncthreads();
    const int f = t >> 2;
    #pragma unroll
    for (int c = 0; c < 2; ++c) {
        int pg = (t & 3) * 2 + c;
        int jg = pg ^ (f & 7);
        bf16x8 o;
        #pragma unroll
        for (int jo = 0; jo < 8; ++jo)
            o[jo] = (__bf16)tile[jg * 8 + jo][f];
        *(bf16x8*)&whtsw[((size_t)(h * 64 + f)) * NN + T * 64 + pg * 8] = o;
    }
}

// ---------------- fused masked softmax + PV via MFMA (j-split, unnormalized) ----------------
__global__ __launch_bounds__(256) void k_attn(const unsigned long long* __restrict__ bm_,
                                              const __bf16* __restrict__ whtsw,
                                              const float* __restrict__ f1T,
                                              const float* __restrict__ f2T,
                                              float* __restrict__ oacc,
                                              float* __restrict__ lsumg) {
    __shared__ alignas(16) __bf16 Ps[2][64 * 64];
    __shared__ alignas(16) __bf16 Ws[2][64 * 64];
    __shared__ float f1s[64];

    const int t   = threadIdx.x;
    const int wv  = t >> 6, l = t & 63;
    const int gi0 = blockIdx.x * 64;
    const int h   = blockIdx.y;
    const int jt0 = blockIdx.z * 32;   // 2-way j-split: 32 tiles per block

    if (t < 64) f1s[t] = f1T[h * NN + gi0 + t];
    __syncthreads();

    const int ip = t >> 2;
    const int jq = t & 3;
    const float f1v = f1s[ip];
    const unsigned long long* bmrow = &bm_[(size_t)(gi0 + ip) * 64];
    const int swP = (ip & 7) << 4;

    const int lm = l & 15, lk = l >> 4;
    const int iA    = wv * 16 + lm;
    const int baseA = iA * 128 + lk * 16;
    const int swA   = (iA & 7) << 4;
    const int swB   = (lm & 7) << 4;
    f32x4 acc[4] = {};
    f32x4 accl = {};
    bf16x8 ones;
    #pragma unroll
    for (int e = 0; e < 8; ++e) ones[e] = (__bf16)1.0f;

    const __bf16* wbase = &whtsw[(size_t)(h * 64) * NN];

    auto stage_W = [&](int jt, int bb) {
        #pragma unroll
        for (int k = 0; k < 2; ++k) {
            int n16 = t + k * 256;
            int f = n16 >> 3, jg = n16 & 7;
            const __bf16* src = wbase + (size_t)f * NN + jt * 64 + jg * 8;
            __builtin_amdgcn_global_load_lds(
                (const __attribute__((address_space(1))) void*)src,
                (__attribute__((address_space(3))) void*)((char*)&Ws[bb][0] + n16 * 16),
                16, 0, 0);
        }
    };

    auto compute_P = [&](int jt, int bb) {
        unsigned long long w = bmrow[jt];
        unsigned m16 = (unsigned)((w >> (jq * 16)) & 0xFFFFULL);
        const float4* f2p = (const float4*)&f2T[h * NN + jt * 64 + jq * 16];
        #pragma unroll
        for (int c = 0; c < 2; ++c) {
            bf16x8 pk;
            #pragma unroll
            for (int qq = 0; qq < 2; ++qq) {
                float4 f2v = f2p[c * 2 + qq];
                float ee[4] = {f2v.x, f2v.y, f2v.z, f2v.w};
                #pragma unroll
                for (int e = 0; e < 4; ++e) {
                    float s = f1v + ee[e];                  // pre-scaled by log2e
                    float lr = fmaxf(s, LRELU_ALPHA * s);
                    float p = __builtin_amdgcn_exp2f(lr);
                    p = (m16 & (1u << (c * 8 + qq * 4 + e))) ? p : 0.0f;
                    pk[qq * 4 + e] = (__bf16)p;
                }
            }
            *(bf16x8*)((char*)&Ps[bb][0] + ((ip * 128 + (jq * 2 + c) * 16) ^ swP)) = pk;
        }
    };

    auto do_mfma = [&](int bb) {
        const char* pb = (const char*)&Ps[bb][0];
        const char* wb = (const char*)&Ws[bb][0];
        bf16x8 aF[2];
        #pragma unroll
        for (int ks = 0; ks < 2; ++ks)
            aF[ks] = *(const bf16x8*)(pb + ((baseA | (ks << 6)) ^ swA));
        #pragma unroll
        for (int q = 0; q < 4; ++q) {
            const int baseB = (q * 16 + lm) * 128 + lk * 16;
            #pragma unroll
            for (int ks = 0; ks < 2; ++ks) {
                bf16x8 bF = *(const bf16x8*)(wb + ((baseB | (ks << 6)) ^ swB));
                acc[q] = __builtin_amdgcn_mfma_f32_16x16x32_bf16(aF[ks], bF, acc[q], 0, 0, 0);
            }
        }
        #pragma unroll
        for (int ks = 0; ks < 2; ++ks)   // row-sum via ones-B MFMA
            accl = __builtin_amdgcn_mfma_f32_16x16x32_bf16(aF[ks], ones, accl, 0, 0, 0);
    };

    stage_W(jt0, 0);
    compute_P(jt0, 0);
    for (int jj = 0; jj < 32; ++jj) {
        const int cur = jj & 1, nxt = cur ^ 1;
        __syncthreads();
        if (jj < 31) {
            stage_W(jt0 + jj + 1, nxt);
            compute_P(jt0 + jj + 1, nxt);
        }
        do_mfma(cur);
    }

    #pragma unroll
    for (int q = 0; q < 4; ++q)
        #pragma unroll
        for (int r = 0; r < 4; ++r) {
            int io = wv * 16 + lk * 4 + r;
            atomicAdd(&oacc[(size_t)(gi0 + io) * NFLAT + h * 64 + q * 16 + lm], acc[q][r]);
        }
    if (lm == 0) {
        #pragma unroll
        for (int r = 0; r < 4; ++r)
            atomicAdd(&lsumg[h * NN + gi0 + wv * 16 + lk * 4 + r], accl[r]);
    }
}

// ---------------- normalize + head-sum ----------------
__global__ __launch_bounds__(256) void k_norm(const float* __restrict__ oacc,
                                              const float* __restrict__ lsumg,
                                              float* __restrict__ out) {
    int t = blockIdx.x * 256 + threadIdx.x;
    int i = t >> 4, fq = (t & 15) * 4;
    float4 s = make_float4(0.f, 0.f, 0.f, 0.f);
    #pragma unroll
    for (int h = 0; h < 8; ++h) {
        float inv = 1.0f / (lsumg[h * NN + i] * (float)NH);
        float4 v = *(const float4*)&oacc[(size_t)i * NFLAT + h * 64 + fq];
        s.x = fmaf(v.x, inv, s.x);
        s.y = fmaf(v.y, inv, s.y);
        s.z = fmaf(v.z, inv, s.z);
        s.w = fmaf(v.w, inv, s.w);
    }
    *(float4*)&out[(size_t)i * FOUT + fq] = s;
}

extern "C" void kernel_launch(void* const* d_in, const int* in_sizes, int n_in,
                              void* d_out, int out_size, void* d_ws, size_t ws_size,
                              hipStream_t stream) {
    const float* x   = (const float*)d_in[0];
    const int*   adj = (const int*)d_in[1];
    const float* W   = (const float*)d_in[2];
    const float* a   = (const float*)d_in[3];
    float* out = (float*)d_out;

    char* ws = (char*)d_ws;
    float* Wh    = (float*)ws;   // 8 MiB, dead after k_prep_wht
    float* oacc  = (float*)ws;   // aliases Wh
    ws += (size_t)NN * NFLAT * 4;
    float* f1T = (float*)ws;            ws += (size_t)NH * NN * 4;
    float* f2T = (float*)ws;            ws += (size_t)NH * NN * 4;
    __bf16* whtsw = (__bf16*)ws;        ws += (size_t)NFLAT * NN * 2;
    unsigned long long* bmask = (unsigned long long*)ws; ws += (size_t)NN * NN / 8;
    __bf16* wtsw = (__bf16*)ws;         ws += (size_t)FIN * NFLAT * 2;
    float* Wa = (float*)ws;             ws += (size_t)FIN * 16 * 4;
    float* lsumg = (float*)ws;          ws += (size_t)NH * NN * 4;

    k_bitmask<<<NN * NN / 256, 256, 0, stream>>>(adj, bmask);
    k_wa<<<FIN / 16, 256, 0, stream>>>(W, a, Wa);
    k_f12<<<NN / 16, 256, 0, stream>>>(x, Wa, f1T, f2T);
    k_prep_wt<<<dim3(8, 8), 256, 0, stream>>>(W, wtsw);
    k_gemm<<<dim3(NN / 64, NFLAT / 64), 256, 0, stream>>>(x, wtsw, Wh);
    k_prep_wht<<<dim3(64, NH), 256, 0, stream>>>(Wh, whtsw);
    hipMemsetAsync(oacc, 0, (size_t)NN * NFLAT * 4, stream);
    hipMemsetAsync(lsumg, 0, (size_t)NH * NN * 4, stream);
    k_attn<<<dim3(NN / 64, NH, 2), 256, 0, stream>>>(bmask, whtsw, f1T, f2T, oacc, lsumg);
    k_norm<<<NN * FOUT / 4 / 256, 256, 0, stream>>>(oacc, lsumg, out);
}

// Round 4
// 129.225 us; speedup vs baseline: 3.4052x; 1.0576x over previous
//
#include <hip/hip_runtime.h>

#define LRELU_ALPHA 0.2f

constexpr int NN    = 4096;
constexpr int FIN   = 512;
constexpr int NH    = 8;
constexpr int FOUT  = 64;
constexpr int NFLAT = NH * FOUT; // 512
constexpr float LOG2E = 1.4426950408889634f;

typedef __attribute__((ext_vector_type(8))) __bf16 bf16x8;
typedef __attribute__((ext_vector_type(4))) __bf16 bf16x4;
typedef __attribute__((ext_vector_type(4))) float f32x4;

// ---------------- pack adj into bitmask ----------------
__global__ __launch_bounds__(256) void k_bitmask(const int* __restrict__ adj,
                                                 unsigned long long* __restrict__ bm) {
    size_t idx = (size_t)blockIdx.x * 256 + threadIdx.x;
    int v = adj[idx];
    unsigned long long b = __ballot(v > 0);
    if ((threadIdx.x & 63) == 0) bm[idx >> 6] = b;
}

// ---------------- Wa[k][o] = log2e * sum_f W[k][(o&7)*64+f] * a[(o>>3)*64+f] ----------------
__global__ __launch_bounds__(256) void k_wa(const float* __restrict__ W,
                                            const float* __restrict__ a,
                                            float* __restrict__ Wa) {
    const int t = threadIdx.x;
    const int k = blockIdx.x * 16 + (t >> 4);
    const int o = t & 15;
    const float* wrow = &W[(size_t)k * NFLAT + (o & 7) * 64];
    const float* av   = &a[(o >> 3) * 64];
    float acc = 0.f;
    #pragma unroll 8
    for (int f = 0; f < 64; ++f) acc = fmaf(wrow[f], av[f], acc);
    Wa[k * 16 + o] = acc * LOG2E;
}

// ---------------- f{1,2}T[h][n] = sum_k x[n][k] * Wa[k][o]  (log2e pre-scaled) ----------------
__global__ __launch_bounds__(256) void k_f12(const float* __restrict__ x,
                                             const float* __restrict__ Wa,
                                             float* __restrict__ f1T,
                                             float* __restrict__ f2T) {
    __shared__ float xs[16][512];
    __shared__ float was[512 * 16];
    const int t = threadIdx.x;
    const int n0 = blockIdx.x * 16;
    #pragma unroll
    for (int i = 0; i < 8; ++i) {
        int idx = t + i * 256;
        int r = idx >> 7, cq = idx & 127;
        *(float4*)&xs[r][(cq ^ (r & 3)) * 4] = *(const float4*)&x[(size_t)(n0 + r) * FIN + cq * 4];
        *(float4*)&was[idx * 4] = *(const float4*)&Wa[idx * 4];
    }
    __syncthreads();
    const int o = t & 15, nl = t >> 4;
    float acc = 0.f;
    #pragma unroll 4
    for (int kq = 0; kq < 128; ++kq) {
        float4 xv = *(const float4*)&xs[nl][(kq ^ (nl & 3)) * 4];
        int k0 = kq * 4;
        acc = fmaf(xv.x, was[(k0 + 0) * 16 + o], acc);
        acc = fmaf(xv.y, was[(k0 + 1) * 16 + o], acc);
        acc = fmaf(xv.z, was[(k0 + 2) * 16 + o], acc);
        acc = fmaf(xv.w, was[(k0 + 3) * 16 + o], acc);
    }
    float* dst = (o >> 3) ? f2T : f1T;
    dst[(o & 7) * NN + n0 + nl] = acc;
}

// ---------------- W -> wtsw[kt][f][64k] bf16, group g stored at g^(f&7) ----------------
__global__ __launch_bounds__(256) void k_prep_wt(const float* __restrict__ W,
                                                 __bf16* __restrict__ wtsw) {
    __shared__ float tile[64][68];
    const int t = threadIdx.x;
    const int kt = blockIdx.x;
    const int fb = blockIdx.y * 64;
    {
        const int kk = t >> 2, cq = (t & 3) * 16;
        #pragma unroll
        for (int i = 0; i < 4; ++i)
            *(float4*)&tile[kk][cq + i * 4] =
                *(const float4*)&W[(size_t)(kt * 64 + kk) * NFLAT + fb + cq + i * 4];
    }
    __syncthreads();
    const int fl = t >> 2;
    #pragma unroll
    for (int c = 0; c < 2; ++c) {
        int gs = (t & 3) * 2 + c;
        int g  = gs ^ (fl & 7);
        bf16x8 o;
        #pragma unroll
        for (int jo = 0; jo < 8; ++jo) o[jo] = (__bf16)tile[g * 8 + jo][fl];
        *(bf16x8*)&wtsw[((size_t)(kt * NFLAT + fb + fl)) * 64 + gs * 8] = o;
    }
}

// ---------------- Wh = bf16(x) @ bf16(W) via MFMA -> whtsw directly (transposed+swizzled) ----
// Also zero-fills oacc and lsumg (runs before k_attn).
__global__ __launch_bounds__(256) void k_gemm(const float* __restrict__ x,
                                              const __bf16* __restrict__ wtsw,
                                              __bf16* __restrict__ whtsw,
                                              float* __restrict__ oacc,
                                              float* __restrict__ lsumg) {
    __shared__ alignas(16) __bf16 Bs[2][64 * 64];
    const int t = threadIdx.x, wv = t >> 6, l = t & 63;
    const int bm = blockIdx.x * 64, bn = blockIdx.y * 64;
    const int lm = l & 15, lk = l >> 4;
    const int swB = (lm & 7) << 4;

    // free-rider zero-init: oacc (2M floats over 512 blocks), lsumg (32K floats over 32 blocks)
    {
        const int bid = blockIdx.y * 64 + blockIdx.x;
        float4 z = make_float4(0.f, 0.f, 0.f, 0.f);
        float4* od = (float4*)oacc;
        #pragma unroll
        for (int i = 0; i < 4; ++i) od[(size_t)bid * 1024 + t * 4 + i] = z;
        if (bid < 32) ((float4*)lsumg)[bid * 256 + t] = z;
    }

    f32x4 acc[4] = {};
    auto stageB = [&](int kt, int bb) {
        #pragma unroll
        for (int kq = 0; kq < 2; ++kq) {
            int u = t + kq * 256;
            __builtin_amdgcn_global_load_lds(
                (const __attribute__((address_space(1))) void*)(wtsw + (size_t)(kt * NFLAT + bn) * 64 + u * 8),
                (__attribute__((address_space(3))) void*)((char*)&Bs[bb][0] + u * 16), 16, 0, 0);
        }
    };

    stageB(0, 0);
    const float* xrow = &x[(size_t)(bm + wv * 16 + lm) * FIN + lk * 8];
    for (int kt = 0; kt < 8; ++kt) {
        bf16x8 aF[2];
        #pragma unroll
        for (int ks = 0; ks < 2; ++ks) {
            float4 u0 = *(const float4*)&xrow[kt * 64 + ks * 32];
            float4 u1 = *(const float4*)&xrow[kt * 64 + ks * 32 + 4];
            bf16x8 af;
            af[0] = (__bf16)u0.x; af[1] = (__bf16)u0.y; af[2] = (__bf16)u0.z; af[3] = (__bf16)u0.w;
            af[4] = (__bf16)u1.x; af[5] = (__bf16)u1.y; af[6] = (__bf16)u1.z; af[7] = (__bf16)u1.w;
            aF[ks] = af;
        }
        __syncthreads();
        if (kt < 7) stageB(kt + 1, (kt + 1) & 1);
        const char* wb = (const char*)&Bs[kt & 1][0];
        #pragma unroll
        for (int q = 0; q < 4; ++q) {
            #pragma unroll
            for (int ks = 0; ks < 2; ++ks) {
                bf16x8 bF = *(const bf16x8*)(wb + (((q * 16 + lm) * 128 + lk * 16 + ks * 64) ^ swB));
                acc[q] = __builtin_amdgcn_mfma_f32_16x16x32_bf16(aF[ks], bF, acc[q], 0, 0, 0);
            }
        }
    }
    // epilogue: write whtsw[(h*64+f)*NN + n] with per-64-tile swizzle (group g at g^(f&7))
    const int h = blockIdx.y;                 // NFLAT/64 == NH
    const int g = wv * 2 + (lk >> 1);         // j-group within 64-tile
    const int od = (lk & 1) * 4;              // offset within 8-group
    #pragma unroll
    for (int q = 0; q < 4; ++q) {
        const int f = q * 16 + lm;
        const int pg = g ^ (f & 7);
        bf16x4 o;
        #pragma unroll
        for (int r = 0; r < 4; ++r) o[r] = (__bf16)acc[q][r];
        *(bf16x4*)&whtsw[(size_t)(h * 64 + f) * NN + bm + pg * 8 + od] = o;
    }
}

// ---------------- fused masked softmax + PV via MFMA (j-split=4, unnormalized) ----------------
__global__ __launch_bounds__(256, 6) void k_attn(const unsigned long long* __restrict__ bm_,
                                                 const __bf16* __restrict__ whtsw,
                                                 const float* __restrict__ f1T,
                                                 const float* __restrict__ f2T,
                                                 float* __restrict__ oacc,
                                                 float* __restrict__ lsumg) {
    __shared__ alignas(16) __bf16 Ps[64 * 64];      // single buffer (2 barriers/tile)
    __shared__ alignas(16) __bf16 Ws[2][64 * 64];   // double buffer (hide global latency)
    __shared__ float f1s[64];

    const int t   = threadIdx.x;
    const int wv  = t >> 6, l = t & 63;
    const int gi0 = blockIdx.x * 64;
    const int h   = blockIdx.y;
    constexpr int NT = 16;                          // 64 tiles / jsplit 4
    const int jt0 = blockIdx.z * NT;

    if (t < 64) f1s[t] = f1T[h * NN + gi0 + t];
    __syncthreads();

    const int ip = t >> 2;
    const int jq = t & 3;
    const float f1v = f1s[ip];
    const unsigned long long* bmrow = &bm_[(size_t)(gi0 + ip) * 64];
    const int swP = (ip & 7) << 4;

    const int lm = l & 15, lk = l >> 4;
    const int iA    = wv * 16 + lm;
    const int baseA = iA * 128 + lk * 16;
    const int swA   = (iA & 7) << 4;
    const int swB   = (lm & 7) << 4;
    f32x4 acc[4] = {};
    f32x4 accl = {};
    bf16x8 ones;
    #pragma unroll
    for (int e = 0; e < 8; ++e) ones[e] = (__bf16)1.0f;

    const __bf16* wbase = &whtsw[(size_t)(h * 64) * NN];

    auto stage_W = [&](int jt, int bb) {
        #pragma unroll
        for (int k = 0; k < 2; ++k) {
            int n16 = t + k * 256;
            int f = n16 >> 3, jg = n16 & 7;
            const __bf16* src = wbase + (size_t)f * NN + jt * 64 + jg * 8;
            __builtin_amdgcn_global_load_lds(
                (const __attribute__((address_space(1))) void*)src,
                (__attribute__((address_space(3))) void*)((char*)&Ws[bb][0] + n16 * 16),
                16, 0, 0);
        }
    };

    auto compute_P = [&](int jt) {
        unsigned long long w = bmrow[jt];
        unsigned m16 = (unsigned)((w >> (jq * 16)) & 0xFFFFULL);
        const float4* f2p = (const float4*)&f2T[h * NN + jt * 64 + jq * 16];
        #pragma unroll
        for (int c = 0; c < 2; ++c) {
            bf16x8 pk;
            #pragma unroll
            for (int qq = 0; qq < 2; ++qq) {
                float4 f2v = f2p[c * 2 + qq];
                float ee[4] = {f2v.x, f2v.y, f2v.z, f2v.w};
                #pragma unroll
                for (int e = 0; e < 4; ++e) {
                    float s = f1v + ee[e];                  // pre-scaled by log2e
                    float lr = fmaxf(s, LRELU_ALPHA * s);
                    float p = __builtin_amdgcn_exp2f(lr);
                    p = (m16 & (1u << (c * 8 + qq * 4 + e))) ? p : 0.0f;
                    pk[qq * 4 + e] = (__bf16)p;
                }
            }
            *(bf16x8*)((char*)&Ps[0] + ((ip * 128 + (jq * 2 + c) * 16) ^ swP)) = pk;
        }
    };

    auto do_mfma = [&](int bb) {
        const char* pb = (const char*)&Ps[0];
        const char* wb = (const char*)&Ws[bb][0];
        bf16x8 aF[2];
        #pragma unroll
        for (int ks = 0; ks < 2; ++ks)
            aF[ks] = *(const bf16x8*)(pb + ((baseA | (ks << 6)) ^ swA));
        #pragma unroll
        for (int q = 0; q < 4; ++q) {
            const int baseB = (q * 16 + lm) * 128 + lk * 16;
            #pragma unroll
            for (int ks = 0; ks < 2; ++ks) {
                bf16x8 bF = *(const bf16x8*)(wb + ((baseB | (ks << 6)) ^ swB));
                acc[q] = __builtin_amdgcn_mfma_f32_16x16x32_bf16(aF[ks], bF, acc[q], 0, 0, 0);
            }
        }
        #pragma unroll
        for (int ks = 0; ks < 2; ++ks)   // row-sum via ones-B MFMA
            accl = __builtin_amdgcn_mfma_f32_16x16x32_bf16(aF[ks], ones, accl, 0, 0, 0);
    };

    stage_W(jt0, 0);
    compute_P(jt0);
    for (int jj = 0; jj < NT; ++jj) {
        __syncthreads();                       // Ps ready; Ws[jj&1] drained (barrier waits vmcnt)
        if (jj < NT - 1) stage_W(jt0 + jj + 1, (jj + 1) & 1);
        do_mfma(jj & 1);
        __syncthreads();                       // all reads of Ps done
        if (jj < NT - 1) compute_P(jt0 + jj + 1);
    }

    #pragma unroll
    for (int q = 0; q < 4; ++q)
        #pragma unroll
        for (int r = 0; r < 4; ++r) {
            int io = wv * 16 + lk * 4 + r;
            atomicAdd(&oacc[(size_t)(gi0 + io) * NFLAT + h * 64 + q * 16 + lm], acc[q][r]);
        }
    if (lm == 0) {
        #pragma unroll
        for (int r = 0; r < 4; ++r)
            atomicAdd(&lsumg[h * NN + gi0 + wv * 16 + lk * 4 + r], accl[r]);
    }
}

// ---------------- normalize + head-sum ----------------
__global__ __launch_bounds__(256) void k_norm(const float* __restrict__ oacc,
                                              const float* __restrict__ lsumg,
                                              float* __restrict__ out) {
    int t = blockIdx.x * 256 + threadIdx.x;
    int i = t >> 4, fq = (t & 15) * 4;
    float4 s = make_float4(0.f, 0.f, 0.f, 0.f);
    #pragma unroll
    for (int h = 0; h < 8; ++h) {
        float inv = 1.0f / (lsumg[h * NN + i] * (float)NH);
        float4 v = *(const float4*)&oacc[(size_t)i * NFLAT + h * 64 + fq];
        s.x = fmaf(v.x, inv, s.x);
        s.y = fmaf(v.y, inv, s.y);
        s.z = fmaf(v.z, inv, s.z);
        s.w = fmaf(v.w, inv, s.w);
    }
    *(float4*)&out[(size_t)i * FOUT + fq] = s;
}

extern "C" void kernel_launch(void* const* d_in, const int* in_sizes, int n_in,
                              void* d_out, int out_size, void* d_ws, size_t ws_size,
                              hipStream_t stream) {
    const float* x   = (const float*)d_in[0];
    const int*   adj = (const int*)d_in[1];
    const float* W   = (const float*)d_in[2];
    const float* a   = (const float*)d_in[3];
    float* out = (float*)d_out;

    char* ws = (char*)d_ws;
    float* oacc = (float*)ws;           ws += (size_t)NN * NFLAT * 4;   // 8 MiB
    float* f1T = (float*)ws;            ws += (size_t)NH * NN * 4;      // 128 KiB
    float* f2T = (float*)ws;            ws += (size_t)NH * NN * 4;      // 128 KiB
    __bf16* whtsw = (__bf16*)ws;        ws += (size_t)NFLAT * NN * 2;   // 4 MiB
    unsigned long long* bmask = (unsigned long long*)ws; ws += (size_t)NN * NN / 8; // 2 MiB
    __bf16* wtsw = (__bf16*)ws;         ws += (size_t)FIN * NFLAT * 2;  // 512 KiB
    float* Wa = (float*)ws;             ws += (size_t)FIN * 16 * 4;     // 32 KiB
    float* lsumg = (float*)ws;          ws += (size_t)NH * NN * 4;      // 128 KiB

    k_bitmask<<<NN * NN / 256, 256, 0, stream>>>(adj, bmask);
    k_wa<<<FIN / 16, 256, 0, stream>>>(W, a, Wa);
    k_f12<<<NN / 16, 256, 0, stream>>>(x, Wa, f1T, f2T);
    k_prep_wt<<<dim3(8, 8), 256, 0, stream>>>(W, wtsw);
    k_gemm<<<dim3(NN / 64, NFLAT / 64), 256, 0, stream>>>(x, wtsw, whtsw, oacc, lsumg);
    k_attn<<<dim3(NN / 64, NH, 4), 256, 0, stream>>>(bmask, whtsw, f1T, f2T, oacc, lsumg);
    k_norm<<<NN * FOUT / 4 / 256, 256, 0, stream>>>(oacc, lsumg, out);
}

// Round 5
// 128.942 us; speedup vs baseline: 3.4127x; 1.0022x over previous
//
#include <hip/hip_runtime.h>

#define LRELU_ALPHA 0.2f

constexpr int NN    = 4096;
constexpr int FIN   = 512;
constexpr int NH    = 8;
constexpr int FOUT  = 64;
constexpr int NFLAT = NH * FOUT; // 512
constexpr float LOG2E = 1.4426950408889634f;

typedef __attribute__((ext_vector_type(8))) __bf16 bf16x8;
typedef __attribute__((ext_vector_type(4))) __bf16 bf16x4;
typedef __attribute__((ext_vector_type(4))) float f32x4;

// ================= k_prep: bitmask (transposed) + Wa + wtsw, one dispatch =================
// blocks [0, 65536): pack adj -> bmT[jt*NN + i] (u64 of 64 j's)
// blocks [65536, 65600): W -> wtsw (bf16, pre-swizzled for k_gemm's global_load_lds)
// blocks [65600, 65632): Wa[k][o] = log2e * sum_f W[k][(o&7)*64+f] * a[(o>>3)*64+f]
__global__ __launch_bounds__(256) void k_prep(const int* __restrict__ adj,
                                              const float* __restrict__ W,
                                              const float* __restrict__ a,
                                              unsigned long long* __restrict__ bmT,
                                              __bf16* __restrict__ wtsw,
                                              float* __restrict__ Wa) {
    __shared__ float tile[64][68];
    const int bid = blockIdx.x;
    const int t = threadIdx.x;
    if (bid < 65536) {
        size_t idx = (size_t)bid * 256 + t;
        int v = adj[idx];
        unsigned long long b = __ballot(v > 0);
        if ((t & 63) == 0) {
            int i = (int)(idx >> 12);
            int jt = (int)((idx >> 6) & 63);
            bmT[(size_t)jt * NN + i] = b;
        }
    } else if (bid < 65600) {
        const int b2 = bid - 65536;
        const int kt = b2 >> 3;
        const int fb = (b2 & 7) * 64;
        {
            const int kk = t >> 2, cq = (t & 3) * 16;
            #pragma unroll
            for (int i = 0; i < 4; ++i)
                *(float4*)&tile[kk][cq + i * 4] =
                    *(const float4*)&W[(size_t)(kt * 64 + kk) * NFLAT + fb + cq + i * 4];
        }
        __syncthreads();
        const int fl = t >> 2;
        #pragma unroll
        for (int c = 0; c < 2; ++c) {
            int gs = (t & 3) * 2 + c;
            int g  = gs ^ (fl & 7);
            bf16x8 o;
            #pragma unroll
            for (int jo = 0; jo < 8; ++jo) o[jo] = (__bf16)tile[g * 8 + jo][fl];
            *(bf16x8*)&wtsw[((size_t)(kt * NFLAT + fb + fl)) * 64 + gs * 8] = o;
        }
    } else {
        const int k = (bid - 65600) * 16 + (t >> 4);
        const int o = t & 15;
        const float* wrow = &W[(size_t)k * NFLAT + (o & 7) * 64];
        const float* av   = &a[(o >> 3) * 64];
        float acc = 0.f;
        #pragma unroll 8
        for (int f = 0; f < 64; ++f) acc = fmaf(wrow[f], av[f], acc);
        Wa[k * 16 + o] = acc * LOG2E;
    }
}

// ================= k_main: gemm (-> whtB fragments) + f12, one dispatch =================
// blocks [0,512): Wh = bf16(x) @ bf16(W) via MFMA, epilogue repacks into B-fragment order:
//   whtB[((jt*NH + h)*8 + q*2+ks)*512 + l*8 .. +8] = Wh[jt*64 + ks*32 + (l>>4)*8 + e][h*64 + q*16 + (l&15)]
//   also zero-fills oacc and lsumg.
// blocks [512,768): f{1,2}T[h][n] = sum_k x[n][k] * Wa[k][o]   (LDS-free)
__global__ __launch_bounds__(256) void k_main(const float* __restrict__ x,
                                              const __bf16* __restrict__ wtsw,
                                              const float* __restrict__ Wa,
                                              __bf16* __restrict__ whtB,
                                              float* __restrict__ f1T,
                                              float* __restrict__ f2T,
                                              float* __restrict__ oacc,
                                              float* __restrict__ lsumg) {
    __shared__ alignas(16) __bf16 Bs[2][64 * 64];
    const int bid = blockIdx.x;
    const int t = threadIdx.x;
    if (bid < 512) {
        const int wv = t >> 6, l = t & 63;
        const int jt = bid & 63, h = bid >> 6;
        const int bm = jt * 64, bn = h * 64;
        const int lm = l & 15, lk = l >> 4;
        const int swB = (lm & 7) << 4;

        // free-rider zero-init
        {
            float4 z = make_float4(0.f, 0.f, 0.f, 0.f);
            float4* od = (float4*)oacc;
            #pragma unroll
            for (int i = 0; i < 4; ++i) od[(size_t)bid * 1024 + t * 4 + i] = z;
            if (bid < 32) ((float4*)lsumg)[bid * 256 + t] = z;
        }

        f32x4 acc[4] = {};
        auto stageB = [&](int kt, int bb) {
            #pragma unroll
            for (int kq = 0; kq < 2; ++kq) {
                int u = t + kq * 256;
                __builtin_amdgcn_global_load_lds(
                    (const __attribute__((address_space(1))) void*)(wtsw + (size_t)(kt * NFLAT + bn) * 64 + u * 8),
                    (__attribute__((address_space(3))) void*)((char*)&Bs[bb][0] + u * 16), 16, 0, 0);
            }
        };

        stageB(0, 0);
        const float* xrow = &x[(size_t)(bm + wv * 16 + lm) * FIN + lk * 8];
        for (int kt = 0; kt < 8; ++kt) {
            bf16x8 aF[2];
            #pragma unroll
            for (int ks = 0; ks < 2; ++ks) {
                float4 u0 = *(const float4*)&xrow[kt * 64 + ks * 32];
                float4 u1 = *(const float4*)&xrow[kt * 64 + ks * 32 + 4];
                bf16x8 af;
                af[0] = (__bf16)u0.x; af[1] = (__bf16)u0.y; af[2] = (__bf16)u0.z; af[3] = (__bf16)u0.w;
                af[4] = (__bf16)u1.x; af[5] = (__bf16)u1.y; af[6] = (__bf16)u1.z; af[7] = (__bf16)u1.w;
                aF[ks] = af;
            }
            __syncthreads();
            if (kt < 7) stageB(kt + 1, (kt + 1) & 1);
            const char* wb = (const char*)&Bs[kt & 1][0];
            #pragma unroll
            for (int q = 0; q < 4; ++q) {
                #pragma unroll
                for (int ks = 0; ks < 2; ++ks) {
                    bf16x8 bF = *(const bf16x8*)(wb + (((q * 16 + lm) * 128 + lk * 16 + ks * 64) ^ swB));
                    acc[q] = __builtin_amdgcn_mfma_f32_16x16x32_bf16(aF[ks], bF, acc[q], 0, 0, 0);
                }
            }
        }
        // ---- epilogue: transpose in LDS, emit fragment-ordered whtB ----
        __syncthreads();                       // Bs dead
        __bf16* T = (__bf16*)&Bs[0][0];        // [64 f][stride 72] bf16 = 9216 B
        constexpr int TS = 72;
        #pragma unroll
        for (int q = 0; q < 4; ++q) {
            bf16x4 v;
            #pragma unroll
            for (int r = 0; r < 4; ++r) v[r] = (__bf16)acc[q][r];
            *(bf16x4*)&T[(q * 16 + lm) * TS + wv * 16 + lk * 4] = v;
        }
        __syncthreads();
        #pragma unroll
        for (int half = 0; half < 2; ++half) {
            const int fid = (t >> 6) + half * 4;   // 0..7 = q*2+ks
            const int q = fid >> 1, ks = fid & 1;
            const int f = q * 16 + lm, j0 = ks * 32 + lk * 8;
            bf16x8 frag = *(const bf16x8*)&T[f * TS + j0];
            *(bf16x8*)&whtB[(((size_t)jt * NH + h) * 8 + fid) * 512 + l * 8] = frag;
        }
    } else {
        // ---- f12: LDS-free ----
        const int n = (bid - 512) * 16 + (t >> 4);
        const int o = t & 15;
        const float* xrow = &x[(size_t)n * FIN];
        float acc = 0.f;
        for (int k0 = 0; k0 < FIN; k0 += 4) {
            float4 xv = *(const float4*)&xrow[k0];
            acc = fmaf(xv.x, Wa[(k0 + 0) * 16 + o], acc);
            acc = fmaf(xv.y, Wa[(k0 + 1) * 16 + o], acc);
            acc = fmaf(xv.z, Wa[(k0 + 2) * 16 + o], acc);
            acc = fmaf(xv.w, Wa[(k0 + 3) * 16 + o], acc);
        }
        float* dst = (o >> 3) ? f2T : f1T;
        dst[(o & 7) * NN + n] = acc;
    }
}

// ================= k_attn: fused masked softmax + PV, ZERO LDS, ZERO barriers =================
// Each thread computes exactly its MFMA A-fragment's 16 P elements in registers;
// B fragments load directly from fragment-ordered whtB (L2-resident).
__global__ __launch_bounds__(256, 5) void k_attn(const unsigned long long* __restrict__ bmT,
                                                 const __bf16* __restrict__ whtB,
                                                 const float* __restrict__ f1T,
                                                 const float* __restrict__ f2T,
                                                 float* __restrict__ oacc,
                                                 float* __restrict__ lsumg) {
    const int t   = threadIdx.x;
    const int wv  = t >> 6, l = t & 63;
    const int gi0 = blockIdx.x * 64;
    const int h   = blockIdx.y;
    constexpr int NT = 16;                      // 64 tiles / jsplit 4
    const int jt0 = blockIdx.z * NT;

    const int lm = l & 15, lk = l >> 4;
    const int iA = wv * 16 + lm;
    const float f1v = f1T[h * NN + gi0 + iA];

    f32x4 acc[4] = {};
    f32x4 accl = {};
    bf16x8 ones;
    #pragma unroll
    for (int e = 0; e < 8; ++e) ones[e] = (__bf16)1.0f;

    for (int jj = 0; jj < NT; ++jj) {
        const int jt = jt0 + jj;
        // ---- B fragments: direct, coalesced global loads (issue early) ----
        const __bf16* bbase = &whtB[(((size_t)jt * NH + h) * 8) * 512 + l * 8];
        bf16x8 bF[4][2];
        #pragma unroll
        for (int q = 0; q < 4; ++q)
            #pragma unroll
            for (int ks = 0; ks < 2; ++ks)
                bF[q][ks] = *(const bf16x8*)(bbase + (q * 2 + ks) * 512);

        // ---- P: compute this lane's A-fragment in registers ----
        unsigned long long mrow = bmT[(size_t)jt * NN + gi0 + iA];
        const float* f2t = &f2T[h * NN + jt * 64];
        bf16x8 aF[2];
        #pragma unroll
        for (int ks = 0; ks < 2; ++ks) {
            const int j0 = ks * 32 + lk * 8;
            float4 fa = *(const float4*)&f2t[j0];
            float4 fb = *(const float4*)&f2t[j0 + 4];
            unsigned m8 = (unsigned)(mrow >> j0) & 0xFFu;
            float ee[8] = {fa.x, fa.y, fa.z, fa.w, fb.x, fb.y, fb.z, fb.w};
            bf16x8 pk;
            #pragma unroll
            for (int e = 0; e < 8; ++e) {
                float s = f1v + ee[e];                    // pre-scaled by log2e
                float lr = fmaxf(s, LRELU_ALPHA * s);
                float p = __builtin_amdgcn_exp2f(lr);
                p = (m8 & (1u << e)) ? p : 0.0f;
                pk[e] = (__bf16)p;
            }
            aF[ks] = pk;
        }

        // ---- MFMA ----
        #pragma unroll
        for (int q = 0; q < 4; ++q) {
            acc[q] = __builtin_amdgcn_mfma_f32_16x16x32_bf16(aF[0], bF[q][0], acc[q], 0, 0, 0);
            acc[q] = __builtin_amdgcn_mfma_f32_16x16x32_bf16(aF[1], bF[q][1], acc[q], 0, 0, 0);
        }
        accl = __builtin_amdgcn_mfma_f32_16x16x32_bf16(aF[0], ones, accl, 0, 0, 0);
        accl = __builtin_amdgcn_mfma_f32_16x16x32_bf16(aF[1], ones, accl, 0, 0, 0);
    }

    #pragma unroll
    for (int q = 0; q < 4; ++q)
        #pragma unroll
        for (int r = 0; r < 4; ++r) {
            int io = wv * 16 + lk * 4 + r;
            atomicAdd(&oacc[(size_t)(gi0 + io) * NFLAT + h * 64 + q * 16 + lm], acc[q][r]);
        }
    if (lm == 0) {
        #pragma unroll
        for (int r = 0; r < 4; ++r)
            atomicAdd(&lsumg[h * NN + gi0 + wv * 16 + lk * 4 + r], accl[r]);
    }
}

// ================= normalize + head-sum =================
__global__ __launch_bounds__(256) void k_norm(const float* __restrict__ oacc,
                                              const float* __restrict__ lsumg,
                                              float* __restrict__ out) {
    int t = blockIdx.x * 256 + threadIdx.x;
    int i = t >> 4, fq = (t & 15) * 4;
    float4 s = make_float4(0.f, 0.f, 0.f, 0.f);
    #pragma unroll
    for (int h = 0; h < 8; ++h) {
        float inv = 1.0f / (lsumg[h * NN + i] * (float)NH);
        float4 v = *(const float4*)&oacc[(size_t)i * NFLAT + h * 64 + fq];
        s.x = fmaf(v.x, inv, s.x);
        s.y = fmaf(v.y, inv, s.y);
        s.z = fmaf(v.z, inv, s.z);
        s.w = fmaf(v.w, inv, s.w);
    }
    *(float4*)&out[(size_t)i * FOUT + fq] = s;
}

extern "C" void kernel_launch(void* const* d_in, const int* in_sizes, int n_in,
                              void* d_out, int out_size, void* d_ws, size_t ws_size,
                              hipStream_t stream) {
    const float* x   = (const float*)d_in[0];
    const int*   adj = (const int*)d_in[1];
    const float* W   = (const float*)d_in[2];
    const float* a   = (const float*)d_in[3];
    float* out = (float*)d_out;

    char* ws = (char*)d_ws;
    float* oacc = (float*)ws;           ws += (size_t)NN * NFLAT * 4;   // 8 MiB
    float* f1T = (float*)ws;            ws += (size_t)NH * NN * 4;      // 128 KiB
    float* f2T = (float*)ws;            ws += (size_t)NH * NN * 4;      // 128 KiB
    __bf16* whtB = (__bf16*)ws;         ws += (size_t)NFLAT * NN * 2;   // 4 MiB
    unsigned long long* bmT = (unsigned long long*)ws; ws += (size_t)NN * NN / 8; // 2 MiB
    __bf16* wtsw = (__bf16*)ws;         ws += (size_t)FIN * NFLAT * 2;  // 512 KiB
    float* Wa = (float*)ws;             ws += (size_t)FIN * 16 * 4;     // 32 KiB
    float* lsumg = (float*)ws;          ws += (size_t)NH * NN * 4;      // 128 KiB

    k_prep<<<65632, 256, 0, stream>>>(adj, W, a, bmT, wtsw, Wa);
    k_main<<<768, 256, 0, stream>>>(x, wtsw, Wa, whtB, f1T, f2T, oacc, lsumg);
    k_attn<<<dim3(NN / 64, NH, 4), 256, 0, stream>>>(bmT, whtB, f1T, f2T, oacc, lsumg);
    k_norm<<<NN * FOUT / 4 / 256, 256, 0, stream>>>(oacc, lsumg, out);
}